// Round 4
// baseline (222.556 us; speedup 1.0000x reference)
//
#include <hip/hip_runtime.h>

// LTU: out[i] = (dot(W[i,:], x) < 0.6*4096 - negcount(W[i,:])) ? 0 : 1
// W: 8192 x 4096 fp32 row-major, x: 4096 fp32, out: 8192 fp32.
// R4: DIAGNOSTIC ROUND — identical kernel to R3, launched 3x.
// dur_us - 180.4 = 2 * T_kernel, separating kernel time from the harness's
// fixed reset cost (536 MB ws poison + W restore) which dominates top-5 rocprof.

#define N_TL1 8192
#define N_INP 4096
#define ROWS_PER_WAVE 2

typedef float vfloat4 __attribute__((ext_vector_type(4)));

__global__ __launch_bounds__(256, 4) void LTU_kernel(const float* __restrict__ x,
                                                     const float* __restrict__ W,
                                                     float* __restrict__ out) {
    const int wave = threadIdx.x >> 6;                         // 0..3
    const int lane = threadIdx.x & 63;
    const int row0 = (blockIdx.x * 4 + wave) * ROWS_PER_WAVE;  // grid = 1024

    const vfloat4* __restrict__ W0 = (const vfloat4*)(W + (size_t)row0 * N_INP);
    const vfloat4* __restrict__ W1 = (const vfloat4*)(W + (size_t)(row0 + 1) * N_INP);
    const vfloat4* __restrict__ xv = (const vfloat4*)x;

    float acc0 = 0.0f, acc1 = 0.0f;
    int   cnt0 = 0,    cnt1 = 0;

    // 1024 vfloat4 per row; 64 lanes -> 16 chunks per row.
    #pragma unroll 4
    for (int it = 0; it < N_INP / 4 / 64; ++it) {
        const int idx = it * 64 + lane;
        vfloat4 xx = xv[idx];
        vfloat4 w0 = __builtin_nontemporal_load(&W0[idx]);
        vfloat4 w1 = __builtin_nontemporal_load(&W1[idx]);
        acc0 += w0.x * xx.x + w0.y * xx.y + w0.z * xx.z + w0.w * xx.w;
        cnt0 += (w0.x < 0.0f) + (w0.y < 0.0f) + (w0.z < 0.0f) + (w0.w < 0.0f);
        acc1 += w1.x * xx.x + w1.y * xx.y + w1.z * xx.z + w1.w * xx.w;
        cnt1 += (w1.x < 0.0f) + (w1.y < 0.0f) + (w1.z < 0.0f) + (w1.w < 0.0f);
    }

    // wave-64 butterfly reduction
    #pragma unroll
    for (int off = 32; off > 0; off >>= 1) {
        acc0 += __shfl_down(acc0, off, 64);
        cnt0 += __shfl_down(cnt0, off, 64);
        acc1 += __shfl_down(acc1, off, 64);
        cnt1 += __shfl_down(cnt1, off, 64);
    }

    if (lane == 0) {
        const float tau0 = 0.6f * (float)N_INP - (float)cnt0;
        const float tau1 = 0.6f * (float)N_INP - (float)cnt1;
        out[row0]     = (acc0 < tau0) ? 0.0f : 1.0f;
        out[row0 + 1] = (acc1 < tau1) ? 0.0f : 1.0f;
    }
}

extern "C" void kernel_launch(void* const* d_in, const int* in_sizes, int n_in,
                              void* d_out, int out_size, void* d_ws, size_t ws_size,
                              hipStream_t stream) {
    const float* x = (const float*)d_in[0];   // [4096,1]
    const float* W = (const float*)d_in[1];   // [8192,4096]
    float* out = (float*)d_out;               // [8192]

    dim3 grid(N_TL1 / (4 * ROWS_PER_WAVE));   // 1024
    dim3 block(256);
    // 3 identical, idempotent launches: dur delta vs R3 = 2 * T_kernel.
    LTU_kernel<<<grid, block, 0, stream>>>(x, W, out);
    LTU_kernel<<<grid, block, 0, stream>>>(x, W, out);
    LTU_kernel<<<grid, block, 0, stream>>>(x, W, out);
}

// Round 5
// 179.694 us; speedup vs baseline: 1.2385x; 1.2385x over previous
//
#include <hip/hip_runtime.h>

// LTU: out[i] = (dot(W[i,:], x) < 0.6*4096 - negcount(W[i,:])) ? 0 : 1
// W: 8192 x 4096 fp32 row-major, x: 4096 fp32, out: 8192 fp32.
// R5 (final): single launch of the R3 kernel.
// Measured via R4's 3x-launch diagnostic: T_kernel ≈ 21.1 µs for 134.2 MB
// of W traffic = ~6.36 TB/s — at the achievable HBM ceiling (harness fills
// hit 6.8 TB/s). Remaining dur_us (~159 µs) is fixed harness reset cost.
// Design: 2 rows/wave (halves x-load instruction overhead), nontemporal W
// loads (streaming; don't evict x from L1/L2), __launch_bounds__(256,4)
// => 4 blocks/CU, 1024 blocks over 256 CUs.

#define N_TL1 8192
#define N_INP 4096
#define ROWS_PER_WAVE 2

typedef float vfloat4 __attribute__((ext_vector_type(4)));

__global__ __launch_bounds__(256, 4) void LTU_kernel(const float* __restrict__ x,
                                                     const float* __restrict__ W,
                                                     float* __restrict__ out) {
    const int wave = threadIdx.x >> 6;                         // 0..3
    const int lane = threadIdx.x & 63;
    const int row0 = (blockIdx.x * 4 + wave) * ROWS_PER_WAVE;  // grid = 1024

    const vfloat4* __restrict__ W0 = (const vfloat4*)(W + (size_t)row0 * N_INP);
    const vfloat4* __restrict__ W1 = (const vfloat4*)(W + (size_t)(row0 + 1) * N_INP);
    const vfloat4* __restrict__ xv = (const vfloat4*)x;

    float acc0 = 0.0f, acc1 = 0.0f;
    int   cnt0 = 0,    cnt1 = 0;

    // 1024 vfloat4 per row; 64 lanes -> 16 chunks per row.
    #pragma unroll 4
    for (int it = 0; it < N_INP / 4 / 64; ++it) {
        const int idx = it * 64 + lane;
        vfloat4 xx = xv[idx];
        vfloat4 w0 = __builtin_nontemporal_load(&W0[idx]);
        vfloat4 w1 = __builtin_nontemporal_load(&W1[idx]);
        acc0 += w0.x * xx.x + w0.y * xx.y + w0.z * xx.z + w0.w * xx.w;
        cnt0 += (w0.x < 0.0f) + (w0.y < 0.0f) + (w0.z < 0.0f) + (w0.w < 0.0f);
        acc1 += w1.x * xx.x + w1.y * xx.y + w1.z * xx.z + w1.w * xx.w;
        cnt1 += (w1.x < 0.0f) + (w1.y < 0.0f) + (w1.z < 0.0f) + (w1.w < 0.0f);
    }

    // wave-64 butterfly reduction
    #pragma unroll
    for (int off = 32; off > 0; off >>= 1) {
        acc0 += __shfl_down(acc0, off, 64);
        cnt0 += __shfl_down(cnt0, off, 64);
        acc1 += __shfl_down(acc1, off, 64);
        cnt1 += __shfl_down(cnt1, off, 64);
    }

    if (lane == 0) {
        const float tau0 = 0.6f * (float)N_INP - (float)cnt0;
        const float tau1 = 0.6f * (float)N_INP - (float)cnt1;
        out[row0]     = (acc0 < tau0) ? 0.0f : 1.0f;
        out[row0 + 1] = (acc1 < tau1) ? 0.0f : 1.0f;
    }
}

extern "C" void kernel_launch(void* const* d_in, const int* in_sizes, int n_in,
                              void* d_out, int out_size, void* d_ws, size_t ws_size,
                              hipStream_t stream) {
    const float* x = (const float*)d_in[0];   // [4096,1]
    const float* W = (const float*)d_in[1];   // [8192,4096]
    float* out = (float*)d_out;               // [8192]

    dim3 grid(N_TL1 / (4 * ROWS_PER_WAVE));   // 1024
    dim3 block(256);
    LTU_kernel<<<grid, block, 0, stream>>>(x, W, out);
}